// Round 13
// baseline (124.927 us; speedup 1.0000x reference)
//
#include <hip/hip_runtime.h>
#include <hip/hip_bf16.h>
#include <stdint.h>

#define NCLS 10
#define B_ 8
#define N_ 16384
#define G_ 64
#define INF_ 1.0e8f

typedef unsigned long long u64;
typedef unsigned int u32;

__device__ __forceinline__ u32 ordf(float f) {
    u32 b = __float_as_uint(f);
    return (b & 0x80000000u) ? ~b : (b | 0x80000000u);
}
__device__ __forceinline__ float unordf(u32 u) {
    u32 b = (u & 0x80000000u) ? (u ^ 0x80000000u) : ~u;
    return __uint_as_float(b);
}

// Op-for-op identical to the validated round-1 eval (contract off).
__device__ __forceinline__ float iou_pair(float px, float pz, float g3x, float g3z) {
#pragma clang fp contract(off)
    float ddx = px - g3x;
    float ddz = pz - g3z;
    float d = sqrtf(ddx * ddx + ddz * ddz);
    float iou = 1.0f - d / 4.0f;
    return fminf(fmaxf(iou, 0.0f), 1.0f);
}

// Cost for an INSIDE pair (is_in == pad > 0). Identical op order to round 1.
__device__ __forceinline__ float cost_pair(float cx, float cy, float sx, float sy,
                                           float ps, float gcx, float gcy,
                                           float pad, float iou) {
#pragma clang fp contract(off)
    float dx = (cx - gcx) / sx;
    float dy = (cy - gcy) / sy;
    float dist = sqrtf(dx * dx + dy * dy) * pad;
    float soft = exp10f(dist - 3.0f);
    float iou_cost = -logf(iou + 1e-7f) * 3.0f;
    float e = expf(-fabsf(ps));
    float sig = (ps >= 0.0f) ? (1.0f / (1.0f + e)) : (e / (1.0f + e));
    float scale = iou - sig;
    float bce = fmaxf(ps, 0.0f) - ps * iou + log1pf(e);
    float cls = bce * (scale * scale);
    return cls + iou_cost + soft;
}

__device__ __forceinline__ u32 wave_max_u32(u32 k) {
#pragma unroll
    for (int off = 32; off >= 1; off >>= 1) {
        u32 o = __shfl_xor(k, off, 64);
        k = (o > k) ? o : k;
    }
    return k;
}
__device__ __forceinline__ u32 wave_min_u32(u32 k) {
#pragma unroll
    for (int off = 32; off >= 1; off >>= 1) {
        u32 o = __shfl_xor(k, off, 64);
        k = (o < k) ? o : k;
    }
    return k;
}

// a keeps max (descending-list slot), v carries min onward
#define INSD(a, v) { float _h = fmaxf(a, v), _l = fminf(a, v); a = _h; v = _l; }
// a keeps min (ascending-list slot), v carries max onward
#define INSA(a, v) { float _l = fminf(a, v), _h = fmaxf(a, v); a = _l; v = _h; }

// ---------------- k1: one-pass per-(b,g) threshold ----------------
// Block = gi. Full scan of N: top-13 iou (named regs, always-insert) +
// inside-guarded cost bottom-14 (named regs). Per-wave extraction ->
// LDS -> wave-0 merge (structure verified in round 7) -> thr_half.
__global__ __launch_bounds__(256) void k1(
    const float* __restrict__ priors,
    const float* __restrict__ pred_bboxes,
    const float* __restrict__ pred_scores,
    const int*   __restrict__ gt_labels,
    const float* __restrict__ gt_bboxes,
    const float* __restrict__ gt_center,
    const float* __restrict__ gt_b3d,
    const float* __restrict__ pad_flag,
    float* __restrict__ thr_half)
{
    __shared__ float s_i[4 * 13];
    __shared__ float s_c[4 * 14];
    int gi = blockIdx.x;
    int b = gi >> 6;
    int tid = threadIdx.x;
    int lane = tid & 63;
    int w = tid >> 6;

    float gx1 = gt_bboxes[gi * 4 + 0], gy1 = gt_bboxes[gi * 4 + 1];
    float gx2 = gt_bboxes[gi * 4 + 2], gy2 = gt_bboxes[gi * 4 + 3];
    float gcx = gt_center[gi * 2 + 0], gcy = gt_center[gi * 2 + 1];
    float g3x = gt_b3d[gi * 7 + 0],   g3z = gt_b3d[gi * 7 + 2];
    float padv = pad_flag[gi];
    int lab = gt_labels[gi];
    const float* pb = pred_bboxes + (size_t)b * N_ * 7;
    const float* sc = pred_scores + (size_t)b * N_ * 10;

    // named-register sorted lists (no arrays -> no scratch)
    float i0 = -1.0f, i1 = -1.0f, i2 = -1.0f, i3 = -1.0f, i4 = -1.0f,
          i5 = -1.0f, i6 = -1.0f, i7 = -1.0f, i8 = -1.0f, i9 = -1.0f,
          i10 = -1.0f, i11 = -1.0f, i12 = -1.0f;
    float c0 = INF_, c1 = INF_, c2 = INF_, c3 = INF_, c4 = INF_,
          c5 = INF_, c6 = INF_, c7 = INF_, c8 = INF_, c9 = INF_,
          c10 = INF_, c11 = INF_, c12 = INF_, c13 = INF_;

    for (int it = 0; it < 64; ++it) {
        int n = (it << 8) | tid;                  // coalesced across threads
        float4 pr = ((const float4*)priors)[n];
        float px = pb[n * 7 + 0];
        float pz = pb[n * 7 + 2];
        float iou = iou_pair(px, pz, g3x, g3z);
        float v = iou;
        INSD(i0, v) INSD(i1, v) INSD(i2, v) INSD(i3, v) INSD(i4, v)
        INSD(i5, v) INSD(i6, v) INSD(i7, v) INSD(i8, v) INSD(i9, v)
        INSD(i10, v) INSD(i11, v) INSD(i12, v)
        bool isin = (pr.x > gx1) && (pr.y > gy1) && (pr.x < gx2) && (pr.y < gy2)
                    && (padv > 0.0f);
        if (isin) {
            float ps = sc[n * 10 + lab];
            float cst = cost_pair(pr.x, pr.y, pr.z, pr.w, ps, gcx, gcy, padv, iou);
            float u = cst;
            INSA(c0, u) INSA(c1, u) INSA(c2, u) INSA(c3, u) INSA(c4, u)
            INSA(c5, u) INSA(c6, u) INSA(c7, u) INSA(c8, u) INSA(c9, u)
            INSA(c10, u) INSA(c11, u) INSA(c12, u) INSA(c13, u)
        }
    }

    // per-wave top-13 iou extraction (descending; named-reg rotate pop)
    {
        float keepv = 0.0f;
        for (int r = 0; r < 13; ++r) {
            u32 mykey = ordf(i0);
            u32 m = wave_max_u32(mykey);
            if (lane == r) keepv = unordf(m);
            int winner = __ffsll(__ballot(mykey == m)) - 1;
            bool win = (lane == winner);
            i0 = win ? i1 : i0;   i1 = win ? i2 : i1;   i2 = win ? i3 : i2;
            i3 = win ? i4 : i3;   i4 = win ? i5 : i4;   i5 = win ? i6 : i5;
            i6 = win ? i7 : i6;   i7 = win ? i8 : i7;   i8 = win ? i9 : i8;
            i9 = win ? i10 : i9;  i10 = win ? i11 : i10; i11 = win ? i12 : i11;
            i12 = win ? -3.0e38f : i12;
        }
        if (lane < 13) s_i[w * 13 + lane] = keepv;
    }
    // per-wave bottom-14 cost extraction (ascending)
    {
        float keepc = 0.0f;
        for (int r = 0; r < 14; ++r) {
            u32 mykey = ordf(c0);
            u32 m = wave_min_u32(mykey);
            if (lane == r) keepc = unordf(m);
            int winner = __ffsll(__ballot(mykey == m)) - 1;
            bool win = (lane == winner);
            c0 = win ? c1 : c0;   c1 = win ? c2 : c1;   c2 = win ? c3 : c2;
            c3 = win ? c4 : c3;   c4 = win ? c5 : c4;   c5 = win ? c6 : c5;
            c6 = win ? c7 : c6;   c7 = win ? c8 : c7;   c8 = win ? c9 : c8;
            c9 = win ? c10 : c9;  c10 = win ? c11 : c10; c11 = win ? c12 : c11;
            c12 = win ? c13 : c12; c13 = win ? 3.0e38f : c13;
        }
        if (lane < 14) s_c[w * 14 + lane] = keepc;
    }
    __syncthreads();

    if (w == 0) {
        // merge 52 iou partials -> ks (descending-order sum)
        float vi = (lane < 52) ? s_i[lane] : -3.0e38f;
        float sum13 = 0.0f;
        for (int r = 0; r < 13; ++r) {
            u32 mykey = ordf(vi);
            u32 m = wave_max_u32(mykey);
            sum13 += unordf(m);
            int winner = __ffsll(__ballot(mykey == m)) - 1;
            if (lane == winner) vi = -3.0e38f;
        }
        int ks = (int)sum13;
        if (ks < 1) ks = 1;

        // merge 56 cost partials -> ck, ckm1
        float vc = (lane < 56) ? s_c[lane] : 3.0e38f;
        float ck = INF_, ckm1 = INF_;
        for (int r = 0; r < 14; ++r) {
            u32 mykey = ordf(vc);
            u32 m = wave_min_u32(mykey);
            float vm = unordf(m);
            if (r == ks - 1) ckm1 = vm;
            if (r == ks)     ck = vm;
            int winner = __ffsll(__ballot(mykey == m)) - 1;
            if (lane == winner) vc = 3.0e38f;
        }
        if (lane == 0) thr_half[gi] = 0.5f * (ck + ckm1);
    }
}

// ---------------- k2: matching compute + coalesced bit expansion ----------
// Verbatim round-12 matching logic; inside mask recomputed locally
// (cheap uniform compares) instead of read from a mask64 buffer.
__global__ __launch_bounds__(256) void k2(
    const float* __restrict__ priors,
    const float* __restrict__ pred_bboxes,
    const float* __restrict__ pred_scores,
    const int*   __restrict__ gt_labels,
    const float* __restrict__ gt_bboxes,
    const float* __restrict__ gt_center,
    const float* __restrict__ gt_b3d,
    const float* __restrict__ pad_flag,
    const float* __restrict__ thr_half,
    float* __restrict__ out)
{
    __shared__ float s_gcx[G_], s_gcy[G_], s_g3x[G_], s_g3z[G_];
    __shared__ float s_pad[G_], s_thr[G_];
    __shared__ int   s_lab[G_];
    __shared__ u64   s_words[256];

    int b = blockIdx.x >> 6;
    int n0b = (blockIdx.x & 63) << 8;          // first prior of this block
    int n = n0b | threadIdx.x;
    size_t t = (size_t)b * N_ + n;

    if (threadIdx.x < G_) {
        int gi = b * G_ + threadIdx.x;
        s_gcx[threadIdx.x] = gt_center[gi * 2 + 0];
        s_gcy[threadIdx.x] = gt_center[gi * 2 + 1];
        s_g3x[threadIdx.x] = gt_b3d[gi * 7 + 0];
        s_g3z[threadIdx.x] = gt_b3d[gi * 7 + 2];
        s_pad[threadIdx.x] = pad_flag[gi];
        s_thr[threadIdx.x] = thr_half[gi];
        s_lab[threadIdx.x] = gt_labels[gi];
    }

    const float* pb = pred_bboxes + (size_t)b * N_ * 7;
    const float* sc = pred_scores + (size_t)b * N_ * 10;
    float4 pr = ((const float4*)priors)[n];
    float px = pb[n * 7 + 0];
    float pz = pb[n * 7 + 2];

    // local inside-mask recompute (identical compares to prior rounds)
    u64 m = 0;
#pragma unroll 8
    for (int g = 0; g < G_; ++g) {
        int gi = b * G_ + g;                  // uniform
        float4 gbb = ((const float4*)gt_bboxes)[gi];
        float padv = pad_flag[gi];
        bool isin = (pr.x > gbb.x) && (pr.y > gbb.y) && (pr.x < gbb.z)
                    && (pr.y < gbb.w) && (padv > 0.0f);
        m |= ((u64)isin) << g;
    }
    __syncthreads();

    // init = g 0 (argmin over all-INF costs returns index 0)
    float iouC = iou_pair(px, pz, s_g3x[0], s_g3z[0]);
    float costC = INF_;
    int   labC = s_lab[0];

    float iouM = 0.0f, costM = 3.0e38f;
    int   labM = 0, argM = 0;
    u64 mmatch = 0;

    while (m) {
        int g = __ffsll(m) - 1;
        m &= m - 1;
        float gcx = s_gcx[g], gcy = s_gcy[g];
        float g3x = s_g3x[g], g3z = s_g3z[g];
        float padg = s_pad[g];
        int   labg = s_lab[g];
        float th = s_thr[g];
        float ps = sc[n * 10 + labg];
        float iou = iou_pair(px, pz, g3x, g3z);
        float c = cost_pair(pr.x, pr.y, pr.z, pr.w, ps, gcx, gcy, padg, iou);
        if (c < costC) { costC = c; iouC = iou; labC = labg; }
        if (c <= th * padg) {
            mmatch |= 1ull << g;
            if (c < costM) { costM = c; iouM = iou; labM = labg; argM = g; }
        }
    }
    int cm = __popcll(mmatch);
    bool matched = cm > 0;
    u64 outm = (cm > 1) ? (1ull << argM) : mmatch;
    float metric = matched ? iouM : iouC;
    float olab = matched ? (float)labM
                         : ((iouC < 1e-7f) ? (float)NCLS : (float)labC);

    float* out_lab = out;
    float* out_w   = out + (size_t)B_ * N_;
    float* out_met = out + (size_t)2 * B_ * N_;
    float* out_mat = out + (size_t)3 * B_ * N_;
    out_lab[t] = olab;
    out_w[t]   = 1.0f;
    out_met[t] = metric;
    s_words[threadIdx.x] = outm;
    __syncthreads();

    // expand 256 words -> 256 rows x 64 floats, coalesced float4 stores
    int q  = threadIdx.x & 3;                  // 16-col quarter
    int r0 = threadIdx.x >> 2;                 // base row 0..63
    size_t rowbase = (size_t)b * N_ + n0b;
#pragma unroll
    for (int it = 0; it < 4; ++it) {
        int row = r0 + (it << 6);
        u64 wv = s_words[row];
        u32 bits = (u32)(wv >> (q * 16)) & 0xffffu;
        float* dst = out_mat + (rowbase + row) * 64 + q * 16;
#pragma unroll
        for (int jj = 0; jj < 4; ++jj) {
            float4 f;
            f.x = (bits >> (jj * 4 + 0)) & 1u ? 1.0f : 0.0f;
            f.y = (bits >> (jj * 4 + 1)) & 1u ? 1.0f : 0.0f;
            f.z = (bits >> (jj * 4 + 2)) & 1u ? 1.0f : 0.0f;
            f.w = (bits >> (jj * 4 + 3)) & 1u ? 1.0f : 0.0f;
            ((float4*)dst)[jj] = f;
        }
    }
}

extern "C" void kernel_launch(void* const* d_in, const int* in_sizes, int n_in,
                              void* d_out, int out_size, void* d_ws, size_t ws_size,
                              hipStream_t stream)
{
    const float* pred_bboxes = (const float*)d_in[0];
    const float* pred_scores = (const float*)d_in[1];
    const float* priors      = (const float*)d_in[2];
    const int*   gt_labels   = (const int*)d_in[3];
    const float* gt_bboxes   = (const float*)d_in[4];
    const float* gt_center   = (const float*)d_in[5];
    const float* gt_b3d      = (const float*)d_in[6];
    const float* pad_flag    = (const float*)d_in[7];
    float* out = (float*)d_out;

    float* thr_half = (float*)d_ws;            // 512 floats

    k1<<<512, 256, 0, stream>>>(priors, pred_bboxes, pred_scores, gt_labels,
                                gt_bboxes, gt_center, gt_b3d, pad_flag,
                                thr_half);
    k2<<<512, 256, 0, stream>>>(priors, pred_bboxes, pred_scores, gt_labels,
                                gt_bboxes, gt_center, gt_b3d, pad_flag,
                                thr_half, out);
}